// Round 1
// baseline (324.685 us; speedup 1.0000x reference)
//
#include <hip/hip_runtime.h>

// LSTM scan, B=8192 chains, T=2048 steps, D=H=2. 8 lanes/element.
// Round 8: r2-carry chain cut. The carried nonlinearity is now
// r2 = 1/(1+exp2(cs)) = (1-tanh(c))/2 instead of tc = tanh(c); the affine
// tc = 1-2*r2 is folded into the gate coefficients built OFF-CHAIN during
// the trans window:
//   g = V2Own*r2 + V2Oth*r2o + axW,  V2 = -2*a*wh*sigma(o),
//   axW = wx.x + (bias + a*wh_own*sigma_o + a*wh_oth*sigma_o)  ["biasW"]
// This removes the fma(tc) from the per-step dependency cycle (15 -> 14
// chained ops); the col-swap DPP runs in parallel with the inner gate fma.
// Also: the Z cndmask is gone — the sigma_o quad-perm broadcasts source
// quad0 from mv and quad1 from n directly (dual-source masked DPPs).
// Net instruction count unchanged (27/step), chain -1 fma.
//
// Lanes (q=tid&7): l0:i0 l1:i1 l2:f0 l3:f1 l4:o1 l5:o0 l6:g1 l7:g0
// mirror pairs (0,7)(1,6)(2,5)(3,4) = i<->g, f<->o.
// col(l) = (q&1)^((q>>2)&1): l0:0 l1:1 l2:0 l3:1 l4:1 l5:0 l6:1 l7:0.

#define LOG2E 1.4426950408889634f

template <int CTRL>
__device__ __forceinline__ float qdpp(float v) {
    int i = __builtin_bit_cast(int, v);
    i = __builtin_amdgcn_update_dpp(0, i, CTRL, 0xF, 0xF, true);
    return __builtin_bit_cast(float, i);
}
// masked merge DPP: lanes outside row/bank mask keep `old`
template <int CTRL, int BANK>
__device__ __forceinline__ float mdpp(float old, float v) {
    int i = __builtin_amdgcn_update_dpp(__builtin_bit_cast(int, old),
                                        __builtin_bit_cast(int, v),
                                        CTRL, 0xF, BANK, false);
    return __builtin_bit_cast(float, i);
}
#define DPP_MIRROR8 0x141  // row_half_mirror: lane i <-> 7-i
#define DPP_SWAP2   0x4E   // quad_perm(2,3,0,1)
#define DPP_COLSWP  0xB1   // quad_perm(1,0,3,2): adjacent-lane (other col)
#define DPP_ZB_OWN0 0xEE   // quad_perm(2,3,2,3)  (quad0: sigma_o own-col, from mv)
#define DPP_ZB_OWN1 0x44   // quad_perm(0,1,0,1)  (quad1, from n)
#define DPP_ZB_OTH0 0xBB   // quad_perm(3,2,3,2)  (quad0, from mv)
#define DPP_ZB_OTH1 0x11   // quad_perm(1,0,1,0)  (quad1, from n)

__global__ __launch_bounds__(64, 1) void lstm_oct_nh_kernel(
    const float* __restrict__ x,
    const float* __restrict__ h0,
    const float* __restrict__ c0,
    const float* __restrict__ w_ih,
    const float* __restrict__ w_hh,
    const float* __restrict__ b_ih,
    const float* __restrict__ b_hh,
    float* __restrict__ out,
    int B, int T)
{
    const int tid = blockIdx.x * blockDim.x + threadIdx.x;
    const int e = tid >> 3;
    const int q = tid & 7;
    if (e >= B) return;

    const int r = (q < 4) ? q : 11 - q;   // gate row (i0,i1,f0,f1,g0,g1,o0,o1)
    const bool isTanh = (q >= 6);
    const bool sel45  = (q == 4) || (q == 5);
    const bool selMid = (q >= 2) && (q <= 5);
    const int col = (q & 1) ^ ((q >> 2) & 1);

    // exp2 arg scale: sigma lanes -log2e, tanh lanes +2*log2e (prefolded).
    // nonlin: n = m*rcp(1+exp2(garg)) + d ; tanh lanes emit 2L*tanh(g).
    const float a = isTanh ? (2.0f * LOG2E) : (-LOG2E);
    const float m = isTanh ? (-4.0f * LOG2E) : 1.0f;
    const float d = isTanh ? (2.0f * LOG2E) : 0.0f;

    const float wx0 = w_ih[2 * r] * a, wx1 = w_ih[2 * r + 1] * a;
    const float bias = (b_ih[r] + b_hh[r]) * a;
    const float AwhOwn = w_hh[2 * r + col] * a;
    const float AwhOth = w_hh[2 * r + (1 - col)] * a;
    const float Awh2Own = -2.0f * AwhOwn;   // r2-form gate coefficients
    const float Awh2Oth = -2.0f * AwhOth;

    // Loop state:
    //   r2 = (1 - tanh(c))/2 own col; seeded with (1-h0)/2 + sigma_o=1 so
    //        step 1 computes g = a*(wx.x + b + wh.h0) exactly.
    //   cs = c scaled by 2*log2e.
    //   V2Own/V2Oth = -2*a*wh*sigma_o ; biasW = bias + a*wh*sigma_o (both cols).
    float r2 = fmaf(-0.5f, h0[2 * e + col], 0.5f);
    float cs = c0[2 * e + col] * (2.0f * LOG2E);
    float V2Own = Awh2Own;
    float V2Oth = Awh2Oth;
    float biasW = bias + AwhOwn + AwhOth;

    const int NI = T >> 1;
    const float4* __restrict__ xp =
        reinterpret_cast<const float4*>(x) + (size_t)e * NI;

    auto step = [&](float x0, float x1) {
        // ---- chain: gate from carried (r2, V2, biasW) ----
        float r2o = qdpp<DPP_COLSWP>(r2);            // other col (|| inner fma)
        float axW = fmaf(wx1, x1, fmaf(wx0, x0, biasW));  // off-chain
        float g   = fmaf(V2Oth, r2o, fmaf(V2Own, r2, axW));
        float n   = fmaf(m, __builtin_amdgcn_rcpf(1.0f + __builtin_amdgcn_exp2f(g)), d);
        float mv  = qdpp<DPP_MIRROR8>(n);
        float X = sel45 ? mv : n;                    // sigma_i|sigma_f|t'g side
        float Y = selMid ? cs : mv;                  // c' | partner nonlin
        float p = X * Y;
        // c update (off main chain; needed next step + epilogue)
        float ps = qdpp<DPP_SWAP2>(p);
        cs = p + ps;
        // r2 via exp2-product: exp2(cs) = exp2(p)*swap(exp2(p))
        float Ep  = __builtin_amdgcn_exp2f(p);
        float Eps = qdpp<DPP_SWAP2>(Ep);
        r2 = __builtin_amdgcn_rcpf(fmaf(Ep, Eps, 1.0f));
        // ---- off-chain (fills the trans window): next-step coeffs from
        // sigma_o, sourced directly from mv (quad0) and n (quad1).
        float zbOwn = mdpp<DPP_ZB_OWN0, 0x5>(mv, mv);
        zbOwn = mdpp<DPP_ZB_OWN1, 0xA>(zbOwn, n);
        float zbOth = mdpp<DPP_ZB_OTH0, 0x5>(mv, mv);
        zbOth = mdpp<DPP_ZB_OTH1, 0xA>(zbOth, n);
        V2Own = Awh2Own * zbOwn;
        V2Oth = Awh2Oth * zbOth;
        biasW = fmaf(AwhOwn, zbOwn, fmaf(AwhOth, zbOth, bias));
    };

    constexpr int BV = 8;              // float4s per buffer = 16 timesteps
    float4 A[BV], Bb[BV];

    auto loadbuf = [&](float4* buf, int batch) {
#pragma unroll
        for (int j = 0; j < BV; ++j) buf[j] = xp[batch * BV + j];
    };
    auto consume = [&](const float4* buf) {
#pragma unroll
        for (int j = 0; j < BV; ++j) {
            step(buf[j].x, buf[j].y);
            step(buf[j].z, buf[j].w);
        }
    };

    const int nb = NI / BV;
    int bi = 0;
    if (nb >= 2) {
        loadbuf(A, 0);
        loadbuf(Bb, 1);
        for (bi = 0; bi + 1 < nb; bi += 2) {
            consume(A);
            if (bi + 2 < nb) loadbuf(A, bi + 2);
            consume(Bb);
            if (bi + 3 < nb) loadbuf(Bb, bi + 3);
        }
        if (bi < nb) { consume(A); ++bi; }
    }
    for (int i = bi * BV; i < NI; ++i) {   // tail (empty for T=2048)
        float4 v = xp[i];
        step(v.x, v.y);
        step(v.z, v.w);
    }

    // cs = 2L*c -> c = cs * ln2/2
    if (q < 2) out[2 * e + q] = cs * (0.5f / LOG2E);
}

extern "C" void kernel_launch(void* const* d_in, const int* in_sizes, int n_in,
                              void* d_out, int out_size, void* d_ws, size_t ws_size,
                              hipStream_t stream) {
    const float* x    = (const float*)d_in[0];
    const float* h0   = (const float*)d_in[1];
    const float* c0   = (const float*)d_in[2];
    const float* w_ih = (const float*)d_in[3];
    const float* w_hh = (const float*)d_in[4];
    const float* b_ih = (const float*)d_in[5];
    const float* b_hh = (const float*)d_in[6];
    float* out = (float*)d_out;

    const int B = in_sizes[1] / 2;           // h0 is (B, H=2)
    const int T = in_sizes[0] / (B * 2);     // x is (B, T, D=2)

    const int threads = B * 8;               // 8 lanes per element
    dim3 block(64);
    dim3 grid((threads + 63) / 64);
    hipLaunchKernelGGL(lstm_oct_nh_kernel, grid, block, 0, stream,
                       x, h0, c0, w_ih, w_hh, b_ih, b_hh, out, B, T);
}

// Round 2
// 309.687 us; speedup vs baseline: 1.0484x; 1.0484x over previous
//
#include <hip/hip_runtime.h>

// LSTM scan, B=8192 chains, T=2048 steps, D=H=2. 8 lanes/element.
// Round 9: rebuild-path de-chaining. Round-8 post-mortem showed TWO
// co-critical ~13-level dependency cycles per step; shortening only the
// r2-cycle was null. This round takes the sigma_o rebuild cycle off the
// critical path:
//   - xb = wx0*x0 + wx1*x1 + bias is a pure function of prefetched x,
//     computed OFF the recurrence (was chained through biasW -> axW).
//   - hw = AwhOth*zbOth + (AwhOwn*zbOwn + xb_next) carried per step;
//     gate g = V2Oth*r2o + V2Own*r2 + hw.
//   - zbOth = colswap(zbOwn): one DPP instead of two masked merges.
// Rebuild cycle: n -> mv -> mdpp -> mdpp -> fma -> fma -> fma(g)x2 ->
// exp2 -> add -> rcp  (~10 levels) < r2-cycle (~13) -> single binding cycle.
//
// Lanes (q=tid&7): l0:i0 l1:i1 l2:f0 l3:f1 l4:o1 l5:o0 l6:g1 l7:g0
// mirror pairs (0,7)(1,6)(2,5)(3,4) = i<->g, f<->o.
// col(l) = (q&1)^((q>>2)&1): l0:0 l1:1 l2:0 l3:1 l4:1 l5:0 l6:1 l7:0.

#define LOG2E 1.4426950408889634f

template <int CTRL>
__device__ __forceinline__ float qdpp(float v) {
    int i = __builtin_bit_cast(int, v);
    i = __builtin_amdgcn_update_dpp(0, i, CTRL, 0xF, 0xF, true);
    return __builtin_bit_cast(float, i);
}
// masked merge DPP: lanes outside row/bank mask keep `old`
template <int CTRL, int BANK>
__device__ __forceinline__ float mdpp(float old, float v) {
    int i = __builtin_amdgcn_update_dpp(__builtin_bit_cast(int, old),
                                        __builtin_bit_cast(int, v),
                                        CTRL, 0xF, BANK, false);
    return __builtin_bit_cast(float, i);
}
#define DPP_MIRROR8 0x141  // row_half_mirror: lane i <-> 7-i
#define DPP_SWAP2   0x4E   // quad_perm(2,3,0,1)
#define DPP_COLSWP  0xB1   // quad_perm(1,0,3,2): adjacent-lane (other col)
#define DPP_ZB_OWN0 0xEE   // quad_perm(2,3,2,3)  (quad0: sigma_o own-col, from mv)
#define DPP_ZB_OWN1 0x44   // quad_perm(0,1,0,1)  (quad1, from n)

__global__ __launch_bounds__(64, 1) void lstm_oct_nh_kernel(
    const float* __restrict__ x,
    const float* __restrict__ h0,
    const float* __restrict__ c0,
    const float* __restrict__ w_ih,
    const float* __restrict__ w_hh,
    const float* __restrict__ b_ih,
    const float* __restrict__ b_hh,
    float* __restrict__ out,
    int B, int T)
{
    const int tid = blockIdx.x * blockDim.x + threadIdx.x;
    const int e = tid >> 3;
    const int q = tid & 7;
    if (e >= B) return;

    const int r = (q < 4) ? q : 11 - q;   // gate row (i0,i1,f0,f1,g0,g1,o0,o1)
    const bool isTanh = (q >= 6);
    const bool sel45  = (q == 4) || (q == 5);
    const bool selMid = (q >= 2) && (q <= 5);
    const int col = (q & 1) ^ ((q >> 2) & 1);

    // exp2 arg scale: sigma lanes -log2e, tanh lanes +2*log2e (prefolded).
    // nonlin: n = m*rcp(1+exp2(garg)) + d ; tanh lanes emit 2L*tanh(g).
    const float a = isTanh ? (2.0f * LOG2E) : (-LOG2E);
    const float m = isTanh ? (-4.0f * LOG2E) : 1.0f;
    const float d = isTanh ? (2.0f * LOG2E) : 0.0f;

    const float wx0 = w_ih[2 * r] * a, wx1 = w_ih[2 * r + 1] * a;
    const float bias = (b_ih[r] + b_hh[r]) * a;
    const float AwhOwn = w_hh[2 * r + col] * a;
    const float AwhOth = w_hh[2 * r + (1 - col)] * a;
    const float Awh2Own = -2.0f * AwhOwn;   // r2-form gate coefficients
    const float Awh2Oth = -2.0f * AwhOth;

    // Loop state:
    //   r2 = (1 - tanh(c))/2 own col; seeded with (1-h0)/2 + sigma_o=1 so
    //        step 1 computes g = a*(wx.x + b + wh.h0) exactly.
    //   cs = c scaled by 2*log2e.
    //   V2Own/V2Oth = -2*a*wh*sigma_o
    //   hw = a*(whOwn*sigma_oOwn + whOth*sigma_oOth) + xb(this step)
    float r2 = fmaf(-0.5f, h0[2 * e + col], 0.5f);
    float cs = c0[2 * e + col] * (2.0f * LOG2E);
    float V2Own = Awh2Own;
    float V2Oth = Awh2Oth;
    float hw = 0.0f;   // seeded after first x load

    const int NI = T >> 1;
    const float4* __restrict__ xp =
        reinterpret_cast<const float4*>(x) + (size_t)e * NI;

    // step consumes hw (already contains this step's xb); (x0n,x1n) is the
    // NEXT step's x pair, folded into the rebuilt hw off-chain.
    auto step = [&](float x0n, float x1n) {
        // ---- chain: gate from carried (r2, V2, hw) ----
        float r2o = qdpp<DPP_COLSWP>(r2);            // other col (|| inner fma)
        float g   = fmaf(V2Oth, r2o, fmaf(V2Own, r2, hw));
        float n   = fmaf(m, __builtin_amdgcn_rcpf(1.0f + __builtin_amdgcn_exp2f(g)), d);
        float mv  = qdpp<DPP_MIRROR8>(n);
        float X = sel45 ? mv : n;                    // sigma_i|sigma_f|t'g side
        float Y = selMid ? cs : mv;                  // c' | partner nonlin
        float p = X * Y;
        // c update (off main chain; needed next step + epilogue)
        float ps = qdpp<DPP_SWAP2>(p);
        cs = p + ps;
        // r2 via exp2-product: exp2(cs) = exp2(p)*swap(exp2(p))
        float Ep  = __builtin_amdgcn_exp2f(p);
        float Eps = qdpp<DPP_SWAP2>(Ep);
        r2 = __builtin_amdgcn_rcpf(fmaf(Ep, Eps, 1.0f));
        // ---- off-chain rebuild for next step ----
        float xb = fmaf(wx1, x1n, fmaf(wx0, x0n, bias));   // pure-x, hoistable
        float zbOwn = mdpp<DPP_ZB_OWN0, 0x5>(mv, mv);      // sigma_o own-col
        zbOwn = mdpp<DPP_ZB_OWN1, 0xA>(zbOwn, n);
        float zbOth = qdpp<DPP_COLSWP>(zbOwn);             // other-col = colswap
        V2Own = Awh2Own * zbOwn;
        V2Oth = Awh2Oth * zbOth;
        hw = fmaf(AwhOth, zbOth, fmaf(AwhOwn, zbOwn, xb));
    };

    constexpr int BV = 8;              // float4s per buffer = 16 timesteps
    float4 A[BV], Bb[BV];

    auto loadbuf = [&](float4* buf, int batch) {
#pragma unroll
        for (int j = 0; j < BV; ++j) buf[j] = xp[batch * BV + j];
    };
    // consume 16 steps; (nx0,nx1) = x pair of the step FOLLOWING this buffer
    auto consume = [&](const float4* buf, float nx0, float nx1) {
#pragma unroll
        for (int j = 0; j < BV; ++j) {
            step(buf[j].z, buf[j].w);
            if (j + 1 < BV) step(buf[j + 1].x, buf[j + 1].y);
            else            step(nx0, nx1);
        }
    };

    const int nb = NI / BV;
    int bi = 0;
    float tnx0 = 0.0f, tnx1 = 0.0f;    // first x pair of the tail region
    if (nb >= 2) {
        loadbuf(A, 0);
        loadbuf(Bb, 1);
        hw = AwhOwn + AwhOth + fmaf(wx1, A[0].y, fmaf(wx0, A[0].x, bias));
        if (nb * BV < NI) { float4 t0 = xp[nb * BV]; tnx0 = t0.x; tnx1 = t0.y; }
        for (bi = 0; bi + 1 < nb; bi += 2) {
            const bool moreA = bi + 2 < nb;
            consume(A, Bb[0].x, Bb[0].y);
            if (moreA) loadbuf(A, bi + 2);
            consume(Bb, moreA ? A[0].x : tnx0, moreA ? A[0].y : tnx1);
            if (bi + 3 < nb) loadbuf(Bb, bi + 3);
        }
        if (bi < nb) { consume(A, tnx0, tnx1); ++bi; }
    } else if (NI > 0) {
        float4 v0 = xp[0];
        hw = AwhOwn + AwhOth + fmaf(wx1, v0.y, fmaf(wx0, v0.x, bias));
    }
    for (int i = bi * BV; i < NI; ++i) {   // tail (empty for T=2048)
        float4 v = xp[i];
        step(v.z, v.w);
        if (i + 1 < NI) { float4 w2 = xp[i + 1]; step(w2.x, w2.y); }
        else            step(0.0f, 0.0f);
    }

    // cs = 2L*c -> c = cs * ln2/2
    if (q < 2) out[2 * e + q] = cs * (0.5f / LOG2E);
}

extern "C" void kernel_launch(void* const* d_in, const int* in_sizes, int n_in,
                              void* d_out, int out_size, void* d_ws, size_t ws_size,
                              hipStream_t stream) {
    const float* x    = (const float*)d_in[0];
    const float* h0   = (const float*)d_in[1];
    const float* c0   = (const float*)d_in[2];
    const float* w_ih = (const float*)d_in[3];
    const float* w_hh = (const float*)d_in[4];
    const float* b_ih = (const float*)d_in[5];
    const float* b_hh = (const float*)d_in[6];
    float* out = (float*)d_out;

    const int B = in_sizes[1] / 2;           // h0 is (B, H=2)
    const int T = in_sizes[0] / (B * 2);     // x is (B, T, D=2)

    const int threads = B * 8;               // 8 lanes per element
    dim3 block(64);
    dim3 grid((threads + 63) / 64);
    hipLaunchKernelGGL(lstm_oct_nh_kernel, grid, block, 0, stream,
                       x, h0, c0, w_ih, w_hh, b_ih, b_hh, out, B, T);
}